// Round 1
// baseline (58.354 us; speedup 1.0000x reference)
//
#include <hip/hip_runtime.h>
#include <math.h>

#define NQ   12
#define DIM  4096      // 2^12
#define NL   3
#define NB   512       // batch
#define NT   256       // threads per block
#define PAIRS (DIM/2)  // 2048

__global__ __launch_bounds__(NT) void qdqn_kernel(
    const float* __restrict__ inputs,     // [NB, NQ]
    const float* __restrict__ w_input2,   // [NQ]
    const float* __restrict__ w_output2,  // [2]
    const float* __restrict__ y_weights,  // [NL, NQ]
    const float* __restrict__ z_weights,  // [NL, NQ]
    float* __restrict__ out)              // [NB, 2]
{
    __shared__ float sr[DIM];
    __shared__ float si[DIM];
    __shared__ float cxs[NQ], sxs[NQ];            // RX half-angle cos/sin (layer-invariant)
    __shared__ float u00r[NQ], u00i[NQ], u01r[NQ], u01i[NQ];  // fused U = RY*RX
    __shared__ float hz[NQ];                      // RZ half-angles for current layer
    __shared__ float rbuf[8];

    const int b   = blockIdx.x;
    const int tid = threadIdx.x;

    // ---- init |0...0> ----
    for (int i = tid; i < DIM; i += NT) { sr[i] = 0.0f; si[i] = 0.0f; }
    if (tid == 0) sr[0] = 1.0f;

    // ---- batch-dependent RX half-angles ----
    if (tid < NQ) {
        float a = atanf(inputs[b * NQ + tid] * w_input2[tid]) * 0.5f;
        cxs[tid] = cosf(a);
        sxs[tid] = sinf(a);
    }
    __syncthreads();

    for (int l = 0; l < NL; ++l) {
        // fused per-wire unitary U = RY(theta_y) * RX(theta_x):
        // U00 = cy*cx + i*sy*sx ; U01 = -sy*cx - i*cy*sx
        // U10 = -conj(U01)      ; U11 =  conj(U00)
        if (tid < NQ) {
            float hy = y_weights[l * NQ + tid] * 0.5f;
            float cy = cosf(hy), sy = sinf(hy);
            float cx = cxs[tid], sx = sxs[tid];
            u00r[tid] =  cy * cx;  u00i[tid] =  sy * sx;
            u01r[tid] = -sy * cx;  u01i[tid] = -cy * sx;
            hz[tid]   = z_weights[l * NQ + tid] * 0.5f;
        }
        __syncthreads();

        // ---- 12 fused RY*RX pair passes ----
        for (int w = 0; w < NQ; ++w) {
            const int bbit = NQ - 1 - w;          // qubit w lives at bit (11-w)
            const int half = 1 << bbit;
            const float a00r = u00r[w], a00i = u00i[w];
            const float a01r = u01r[w], a01i = u01i[w];
            #pragma unroll
            for (int p = tid; p < PAIRS; p += NT) {
                int i0 = ((p >> bbit) << (bbit + 1)) | (p & (half - 1));
                int i1 = i0 + half;
                float r0 = sr[i0], m0 = si[i0];
                float r1 = sr[i1], m1 = si[i1];
                // n0 = U00*a0 + U01*a1
                float n0r = a00r * r0 - a00i * m0 + a01r * r1 - a01i * m1;
                float n0i = a00r * m0 + a00i * r0 + a01r * m1 + a01i * r1;
                // n1 = -conj(U01)*a0 + conj(U00)*a1
                float n1r = -a01r * r0 - a01i * m0 + a00r * r1 + a00i * m1;
                float n1i = -a01r * m0 + a01i * r0 + a00r * m1 - a00i * r1;
                sr[i0] = n0r; si[i0] = n0i;
                sr[i1] = n1r; si[i1] = n1i;
            }
            __syncthreads();
        }

        // ---- fused RZ(all wires) + CZ-ring diagonal pass ----
        for (int i = tid; i < DIM; i += NT) {
            float ph = 0.0f;
            #pragma unroll
            for (int w = 0; w < NQ; ++w) {
                ph += ((i >> (NQ - 1 - w)) & 1) ? hz[w] : -hz[w];
            }
            // CZ ring: parity of cyclically-adjacent set-bit pairs
            int r = ((i >> 1) | (i << (NQ - 1))) & (DIM - 1);
            int cnt = __popc(i & r);
            float sgn = (cnt & 1) ? -1.0f : 1.0f;
            float sph, cph;
            sincosf(ph, &sph, &cph);
            float pr = sgn * cph, pi = sgn * sph;
            float rr = sr[i], ii = si[i];
            sr[i] = rr * pr - ii * pi;
            si[i] = rr * pi + ii * pr;
        }
        __syncthreads();
    }

    // ---- expectation values: Z0*Z1 (bits 11,10) and Z2*Z3 (bits 9,8) ----
    float e0 = 0.0f, e1 = 0.0f;
    for (int i = tid; i < DIM; i += NT) {
        float p = sr[i] * sr[i] + si[i] * si[i];
        e0 += (((i >> 11) ^ (i >> 10)) & 1) ? -p : p;
        e1 += (((i >> 9)  ^ (i >> 8))  & 1) ? -p : p;
    }
    // wave64 reduce
    #pragma unroll
    for (int off = 32; off > 0; off >>= 1) {
        e0 += __shfl_down(e0, off);
        e1 += __shfl_down(e1, off);
    }
    const int lane = tid & 63, wv = tid >> 6;
    if (lane == 0) { rbuf[wv] = e0; rbuf[4 + wv] = e1; }
    __syncthreads();
    if (tid == 0) {
        float t0 = rbuf[0] + rbuf[1] + rbuf[2] + rbuf[3];
        float t1 = rbuf[4] + rbuf[5] + rbuf[6] + rbuf[7];
        out[b * 2 + 0] = (1.0f + t0) * 0.5f * w_output2[0];
        out[b * 2 + 1] = (1.0f + t1) * 0.5f * w_output2[1];
    }
}

extern "C" void kernel_launch(void* const* d_in, const int* in_sizes, int n_in,
                              void* d_out, int out_size, void* d_ws, size_t ws_size,
                              hipStream_t stream) {
    const float* inputs    = (const float*)d_in[0];
    const float* w_input2  = (const float*)d_in[1];
    const float* w_output2 = (const float*)d_in[2];
    const float* y_weights = (const float*)d_in[3];
    const float* z_weights = (const float*)d_in[4];
    float* out = (float*)d_out;
    qdqn_kernel<<<NB, NT, 0, stream>>>(inputs, w_input2, w_output2,
                                       y_weights, z_weights, out);
}

// Round 2
// 35.992 us; speedup vs baseline: 1.6213x; 1.6213x over previous
//
#include <hip/hip_runtime.h>
#include <math.h>

#define NQ   12
#define DIM  4096      // 2^12
#define NL   3
#define NB   512       // batch
#define NT   256       // threads per block

// State mapping: amp index i (12 bits) = (tid << 4) | j
//   bits 3..0  -> thread-local j   (register gates)
//   bits 9..4  -> lane id bits 5..0 (shuffle gates)
//   bits 11..10-> wave id bits 1..0 (LDS-exchange gates)
// Per wire: fused U = RZ * RY * RX is SU(2): [[A, B], [-conj(B), conj(A)]]
// Layer-3 RZ and CZ are diagonal phases -> dropped (|amp|^2 unaffected).

__global__ __launch_bounds__(NT) void qdqn_kernel(
    const float* __restrict__ inputs,     // [NB, NQ]
    const float* __restrict__ w_input2,   // [NQ]
    const float* __restrict__ w_output2,  // [2]
    const float* __restrict__ y_weights,  // [NL, NQ]
    const float* __restrict__ z_weights,  // [NL, NQ]
    float* __restrict__ out)              // [NB, 2]
{
    __shared__ float2 ex[NT][17];         // exchange buffer, stride 17 (bank-conflict floor)
    __shared__ float4 gU[NL][NQ];         // per (layer, amp-bit): {Ar, Ai, Br, Bi}
    __shared__ float  rbuf[8];

    const int tid = threadIdx.x;
    const int blk = blockIdx.x;

    // ---- per-(layer, wire) fused 2x2 params, computed by 36 threads ----
    if (tid < NL * NQ) {
        const int l = tid / NQ;
        const int b = tid % NQ;           // amp-bit position
        const int w = NQ - 1 - b;         // wire index (wire w acts on bit 11-w)
        float hx = atanf(inputs[blk * NQ + w] * w_input2[w]) * 0.5f;
        float hy = y_weights[l * NQ + w] * 0.5f;
        float hz = (l == NL - 1) ? 0.0f : z_weights[l * NQ + w] * 0.5f;
        float cx, sx, cy, sy, cz, sz;
        __sincosf(hx, &sx, &cx);
        __sincosf(hy, &sy, &cy);
        __sincosf(hz, &sz, &cz);
        // RY*RX: A0 = cy*cx + i sy*sx ; B0 = -sy*cx - i cy*sx
        float A0r = cy * cx, A0i = sy * sx;
        float B0r = -sy * cx, B0i = -cy * sx;
        // fold RZ: A = e^{-i hz} A0, B = e^{-i hz} B0
        gU[l][b] = make_float4(cz * A0r + sz * A0i, cz * A0i - sz * A0r,
                               cz * B0r + sz * B0i, cz * B0i - sz * B0r);
    }

    // ---- CZ-ring sign mask for this thread's 16 amps (static across layers) ----
    int czm = 0;
    #pragma unroll
    for (int j = 0; j < 16; ++j) {
        int i = (tid << 4) | j;
        int r = ((i >> 1) | (i << (NQ - 1))) & (DIM - 1);
        czm |= (__popc(i & r) & 1) << j;
    }

    // ---- state in registers: |00..0> ----
    float ar[16], ai[16];
    #pragma unroll
    for (int j = 0; j < 16; ++j) { ar[j] = 0.0f; ai[j] = 0.0f; }
    if (tid == 0) ar[0] = 1.0f;

    __syncthreads();   // gU ready

    const int lane = tid & 63;

    for (int l = 0; l < NL; ++l) {
        // ---- register-local gates: amp bits 0..3 ----
        #pragma unroll
        for (int k = 0; k < 4; ++k) {
            const float4 u = gU[l][k];
            const float Ar = u.x, Ai = u.y, Br = u.z, Bi = u.w;
            #pragma unroll
            for (int j0 = 0; j0 < 16; ++j0) {
                if (j0 & (1 << k)) continue;
                const int j1 = j0 | (1 << k);
                float r0 = ar[j0], i0 = ai[j0];
                float r1 = ar[j1], i1 = ai[j1];
                ar[j0] =  Ar * r0 - Ai * i0 + Br * r1 - Bi * i1;
                ai[j0] =  Ar * i0 + Ai * r0 + Br * i1 + Bi * r1;
                ar[j1] = -Br * r0 - Bi * i0 + Ar * r1 + Ai * i1;
                ai[j1] = -Br * i0 + Bi * r0 + Ar * i1 - Ai * r1;
            }
        }

        // ---- shuffle gates: amp bits 4..9 (lane bits 0..5) ----
        #pragma unroll
        for (int m = 0; m < 6; ++m) {
            const float4 u = gU[l][4 + m];
            const int bit = (lane >> m) & 1;
            // bit==0: new = A*own + B*p ; bit==1: new = conj(A)*own - conj(B)*p
            const float Cr = u.x;
            const float Ci = bit ? -u.y : u.y;
            const float Dr = bit ? -u.z : u.z;
            const float Di = u.w;
            #pragma unroll
            for (int j = 0; j < 16; ++j) {
                float pr = __shfl_xor(ar[j], 1 << m);
                float pi = __shfl_xor(ai[j], 1 << m);
                float nr = Cr * ar[j] - Ci * ai[j] + Dr * pr - Di * pi;
                float ni = Cr * ai[j] + Ci * ar[j] + Dr * pi + Di * pr;
                ar[j] = nr; ai[j] = ni;
            }
        }

        // ---- LDS-exchange gates: amp bits 10, 11 (wave bits), chained 2x2 ----
        __syncthreads();   // prior layer's exchange reads complete
        #pragma unroll
        for (int j = 0; j < 16; ++j) ex[tid][j] = make_float2(ar[j], ai[j]);
        __syncthreads();
        {
            const float4 uA = gU[l][10];
            const float4 uB = gU[l][11];
            const int b10 = (tid >> 6) & 1;
            const int b11 = (tid >> 7) & 1;
            const float C0r = uA.x, C0i = b10 ? -uA.y : uA.y;
            const float D0r = b10 ? -uA.z : uA.z, D0i = uA.w;
            const float C1r = uB.x, C1i = b11 ? -uB.y : uB.y;
            const float D1r = b11 ? -uB.z : uB.z, D1i = uB.w;
            const int t64 = tid ^ 64, t128 = tid ^ 128, t192 = tid ^ 192;
            #pragma unroll
            for (int j = 0; j < 16; ++j) {
                float2 q64  = ex[t64][j];
                float2 q128 = ex[t128][j];
                float2 q192 = ex[t192][j];
                // bit-10 gate: own' from (own, q64); mid' from (q128, q192)
                float o1r = C0r * ar[j]   - C0i * ai[j]   + D0r * q64.x  - D0i * q64.y;
                float o1i = C0r * ai[j]   + C0i * ar[j]   + D0r * q64.y  + D0i * q64.x;
                float m1r = C0r * q128.x  - C0i * q128.y  + D0r * q192.x - D0i * q192.y;
                float m1i = C0r * q128.y  + C0i * q128.x  + D0r * q192.y + D0i * q192.x;
                // bit-11 gate: own'' from (own', mid')
                ar[j] = C1r * o1r - C1i * o1i + D1r * m1r - D1i * m1i;
                ai[j] = C1r * o1i + C1i * o1r + D1r * m1i + D1i * m1r;
            }
        }

        // ---- CZ ring (layers 0,1 only; final CZ doesn't affect probs) ----
        if (l < NL - 1) {
            #pragma unroll
            for (int j = 0; j < 16; ++j) {
                const unsigned sb = (unsigned)(((czm >> j) & 1)) << 31;
                ar[j] = __uint_as_float(__float_as_uint(ar[j]) ^ sb);
                ai[j] = __uint_as_float(__float_as_uint(ai[j]) ^ sb);
            }
        }
    }

    // ---- expectations: Z0Z1 -> amp bits 11,10 (uniform per thread);
    //                    Z2Z3 -> amp bits 9,8 (tid bits 5,4) ----
    float p = 0.0f;
    #pragma unroll
    for (int j = 0; j < 16; ++j) p += ar[j] * ar[j] + ai[j] * ai[j];
    float e0 = (((tid >> 7) ^ (tid >> 6)) & 1) ? -p : p;
    float e1 = (((tid >> 5) ^ (tid >> 4)) & 1) ? -p : p;
    #pragma unroll
    for (int off = 32; off; off >>= 1) {
        e0 += __shfl_down(e0, off);
        e1 += __shfl_down(e1, off);
    }
    const int wv = tid >> 6;
    if ((tid & 63) == 0) { rbuf[wv] = e0; rbuf[4 + wv] = e1; }
    __syncthreads();
    if (tid == 0) {
        float t0 = rbuf[0] + rbuf[1] + rbuf[2] + rbuf[3];
        float t1 = rbuf[4] + rbuf[5] + rbuf[6] + rbuf[7];
        out[blk * 2 + 0] = (1.0f + t0) * 0.5f * w_output2[0];
        out[blk * 2 + 1] = (1.0f + t1) * 0.5f * w_output2[1];
    }
}

extern "C" void kernel_launch(void* const* d_in, const int* in_sizes, int n_in,
                              void* d_out, int out_size, void* d_ws, size_t ws_size,
                              hipStream_t stream) {
    const float* inputs    = (const float*)d_in[0];
    const float* w_input2  = (const float*)d_in[1];
    const float* w_output2 = (const float*)d_in[2];
    const float* y_weights = (const float*)d_in[3];
    const float* z_weights = (const float*)d_in[4];
    float* out = (float*)d_out;
    qdqn_kernel<<<NB, NT, 0, stream>>>(inputs, w_input2, w_output2,
                                       y_weights, z_weights, out);
}

// Round 3
// 22.326 us; speedup vs baseline: 2.6137x; 1.6121x over previous
//
#include <hip/hip_runtime.h>
#include <math.h>

#define NQ   12
#define DIM  4096      // 2^12
#define NL   3
#define NB   512       // batch
#define NT   512       // threads per block
#define AMPS 8         // amplitudes per thread (3 local bits)

// Phase p defines which 3 global amp bits are thread-local (register) bits:
//   p=0: bits 2..0   p=1: bits 5..3   p=2: bits 8..6   p=3: bits 11..9
// Gates on local bits are pure register ops; transposes (LDS roundtrip)
// remap between phases. Within a layer all 12 single-qubit gates commute,
// so phase order zigzags across layers to avoid inter-layer transposes.
// Fused per-wire U = RZ*RY*RX (SU(2)): [[A,B],[-conj(B),conj(A)]].
// Layer-3 RZ and all-layer-3 CZ are diagonal -> dropped (probs unaffected).

__device__ __forceinline__ int amp_of(int p, int tid, int j) {
    switch (p) {
        case 0:  return (tid << 3) | j;
        case 1:  return (tid & 7) | (j << 3) | ((tid >> 3) << 6);
        case 2:  return (tid & 63) | (j << 6) | ((tid >> 6) << 9);
        default: return tid | (j << 9);
    }
}
__device__ __forceinline__ int swz(int a) {  // bank swizzle, keeps float2 pairing
    return a ^ (((a >> 4) & 7) << 1);
}

__global__ __launch_bounds__(NT) void qdqn_kernel(
    const float* __restrict__ inputs,     // [NB, NQ]
    const float* __restrict__ w_input2,   // [NQ]
    const float* __restrict__ w_output2,  // [2]
    const float* __restrict__ y_weights,  // [NL, NQ]
    const float* __restrict__ z_weights,  // [NL, NQ]
    float* __restrict__ out)              // [NB, 2]
{
    __shared__ float2 xbuf[DIM];          // 32 KiB transpose buffer
    __shared__ float4 gU[NL][NQ];         // per (layer, amp-bit): {Ar,Ai,Br,Bi}
    __shared__ float  rb0[8], rb1[8];

    const int tid = threadIdx.x;
    const int blk = blockIdx.x;

    // ---- fused per-(layer, amp-bit) 2x2 params ----
    if (tid < NL * NQ) {
        const int l = tid / NQ;
        const int b = tid % NQ;           // amp-bit position
        const int w = NQ - 1 - b;         // wire w acts on amp bit 11-w
        float hx = atanf(inputs[blk * NQ + w] * w_input2[w]) * 0.5f;
        float hy = y_weights[l * NQ + w] * 0.5f;
        float hz = (l == NL - 1) ? 0.0f : z_weights[l * NQ + w] * 0.5f;
        float cx, sx, cy, sy, cz, sz;
        __sincosf(hx, &sx, &cx);
        __sincosf(hy, &sy, &cy);
        __sincosf(hz, &sz, &cz);
        float A0r = cy * cx, A0i = sy * sx;       // RY*RX
        float B0r = -sy * cx, B0i = -cy * sx;
        gU[l][b] = make_float4(cz * A0r + sz * A0i, cz * A0i - sz * A0r,
                               cz * B0r + sz * B0i, cz * B0i - sz * B0r);
    }

    // ---- CZ-ring sign masks for the two mappings where CZ is applied ----
    int czm3 = 0, czm0 = 0;               // end of L0 (phase 3), end of L1 (phase 0)
    #pragma unroll
    for (int j = 0; j < AMPS; ++j) {
        int i3 = tid | (j << 9);
        int r3 = ((i3 >> 1) | (i3 << (NQ - 1))) & (DIM - 1);
        czm3 |= (__popc(i3 & r3) & 1) << j;
        int i0 = (tid << 3) | j;
        int r0 = ((i0 >> 1) | (i0 << (NQ - 1))) & (DIM - 1);
        czm0 |= (__popc(i0 & r0) & 1) << j;
    }

    // ---- state: 8 complex amps in registers, |0...0> ----
    float2 s[AMPS];
    #pragma unroll
    for (int j = 0; j < AMPS; ++j) s[j] = make_float2(0.0f, 0.0f);
    if (tid == 0) s[0].x = 1.0f;

    auto apply_phase = [&](int l, int k) {
        #pragma unroll
        for (int lb = 0; lb < 3; ++lb) {
            const float4 u = gU[l][3 * k + lb];
            const float Ar = u.x, Ai = u.y, Br = u.z, Bi = u.w;
            #pragma unroll
            for (int j0 = 0; j0 < AMPS; ++j0) {
                if (j0 & (1 << lb)) continue;
                const int j1 = j0 | (1 << lb);
                float r0 = s[j0].x, i0 = s[j0].y;
                float r1 = s[j1].x, i1 = s[j1].y;
                s[j0].x =  Ar * r0 - Ai * i0 + Br * r1 - Bi * i1;
                s[j0].y =  Ar * i0 + Ai * r0 + Br * i1 + Bi * r1;
                s[j1].x = -Br * r0 - Bi * i0 + Ar * r1 + Ai * i1;
                s[j1].y = -Br * i0 + Bi * r0 + Ar * i1 - Ai * r1;
            }
        }
    };
    auto transpose = [&](int pf, int pt) {
        __syncthreads();                  // prior reads of xbuf complete
        #pragma unroll
        for (int j = 0; j < AMPS; ++j) xbuf[swz(amp_of(pf, tid, j))] = s[j];
        __syncthreads();
        #pragma unroll
        for (int j = 0; j < AMPS; ++j) s[j] = xbuf[swz(amp_of(pt, tid, j))];
    };
    auto czapply = [&](int mask) {
        #pragma unroll
        for (int j = 0; j < AMPS; ++j) {
            unsigned sb = ((unsigned)((mask >> j) & 1)) << 31;
            s[j].x = __uint_as_float(__float_as_uint(s[j].x) ^ sb);
            s[j].y = __uint_as_float(__float_as_uint(s[j].y) ^ sb);
        }
    };

    __syncthreads();                      // gU ready

    // layer 0: phases 0,1,2,3
    apply_phase(0, 0); transpose(0, 1);
    apply_phase(0, 1); transpose(1, 2);
    apply_phase(0, 2); transpose(2, 3);
    apply_phase(0, 3);
    czapply(czm3);
    // layer 1: phases 3,2,1,0 (already at phase 3 -> no transpose)
    apply_phase(1, 3); transpose(3, 2);
    apply_phase(1, 2); transpose(2, 1);
    apply_phase(1, 1); transpose(1, 0);
    apply_phase(1, 0);
    czapply(czm0);
    // layer 2: phases 0,1,2,3 (already at phase 0); final CZ/RZ dropped
    apply_phase(2, 0); transpose(0, 1);
    apply_phase(2, 1); transpose(1, 2);
    apply_phase(2, 2); transpose(2, 3);
    apply_phase(2, 3);

    // ---- expectations at phase-3 mapping: amp = tid | (j<<9) ----
    // Z0Z1 -> amp bits 11,10 = j2,j1 ; Z2Z3 -> amp bits 9,8 = j0, tid bit 8
    float e0 = 0.0f, in1 = 0.0f;
    #pragma unroll
    for (int j = 0; j < AMPS; ++j) {
        float pw = s[j].x * s[j].x + s[j].y * s[j].y;
        e0  += (((j >> 2) ^ (j >> 1)) & 1) ? -pw : pw;
        in1 += (j & 1) ? -pw : pw;
    }
    float e1 = (tid & 256) ? -in1 : in1;
    #pragma unroll
    for (int off = 32; off; off >>= 1) {
        e0 += __shfl_down(e0, off);
        e1 += __shfl_down(e1, off);
    }
    const int wv = tid >> 6;
    if ((tid & 63) == 0) { rb0[wv] = e0; rb1[wv] = e1; }
    __syncthreads();
    if (tid == 0) {
        float t0 = 0.0f, t1 = 0.0f;
        #pragma unroll
        for (int i = 0; i < 8; ++i) { t0 += rb0[i]; t1 += rb1[i]; }
        out[blk * 2 + 0] = (1.0f + t0) * 0.5f * w_output2[0];
        out[blk * 2 + 1] = (1.0f + t1) * 0.5f * w_output2[1];
    }
}

extern "C" void kernel_launch(void* const* d_in, const int* in_sizes, int n_in,
                              void* d_out, int out_size, void* d_ws, size_t ws_size,
                              hipStream_t stream) {
    const float* inputs    = (const float*)d_in[0];
    const float* w_input2  = (const float*)d_in[1];
    const float* w_output2 = (const float*)d_in[2];
    const float* y_weights = (const float*)d_in[3];
    const float* z_weights = (const float*)d_in[4];
    float* out = (float*)d_out;
    qdqn_kernel<<<NB, NT, 0, stream>>>(inputs, w_input2, w_output2,
                                       y_weights, z_weights, out);
}

// Round 4
// 18.156 us; speedup vs baseline: 3.2141x; 1.2297x over previous
//
#include <hip/hip_runtime.h>
#include <math.h>

#define NQ   12
#define DIM  4096      // 2^12
#define NL   3
#define NB   512       // batch
#define NT   512       // threads per block
#define AMPS 8         // amplitudes per thread (3 local bits)

// Phase p defines which 3 global amp bits are thread-local (register) bits:
//   p=0: bits 2..0   p=1: bits 5..3   p=2: bits 8..6   p=3: bits 11..9
// Circuit-level reductions:
//  - Layer 0 acts on |0..0> with single-qubit gates only -> product state,
//    initialized directly (no gate passes).
//  - Layer 2: RZ + CZ are diagonal (cancel in Z-observable expectation);
//    RX/RY on wires 4..11 have disjoint support from Z0Z1/Z2Z3 -> cancel.
//    Only wires 0..3 (amp bits 11..8) survive.
//  - Layer-1 phase path 0 -> 1 -> 3 -> 2 ends with bit 8 local, so the CZ and
//    the layer-2 bit-8 gate apply at phase 2; one transpose to phase 3 for
//    bits 9..11, where the expectation is computed.
// Fused per-wire U = RZ*RY*RX (SU(2)): [[A,B],[-conj(B),conj(A)]].

__device__ __forceinline__ int amp_of(int p, int tid, int j) {
    switch (p) {
        case 0:  return (tid << 3) | j;
        case 1:  return (tid & 7) | (j << 3) | ((tid >> 3) << 6);
        case 2:  return (tid & 63) | (j << 6) | ((tid >> 6) << 9);
        default: return tid | (j << 9);
    }
}
__device__ __forceinline__ int swz(int a) {  // bank swizzle, keeps float2 pairing
    return a ^ (((a >> 4) & 7) << 1);
}

__global__ __launch_bounds__(NT) void qdqn_kernel(
    const float* __restrict__ inputs,     // [NB, NQ]
    const float* __restrict__ w_input2,   // [NQ]
    const float* __restrict__ w_output2,  // [2]
    const float* __restrict__ y_weights,  // [NL, NQ]
    const float* __restrict__ z_weights,  // [NL, NQ]
    float* __restrict__ out)              // [NB, 2]
{
    __shared__ float2 xA[DIM];            // transpose buffer A (32 KiB)
    __shared__ float2 xB[DIM];            // transpose buffer B (32 KiB)
    __shared__ float4 gU[NL][NQ];         // per (layer, amp-bit): {Ar,Ai,Br,Bi}
    __shared__ float  rb0[8], rb1[8];

    const int tid = threadIdx.x;
    const int blk = blockIdx.x;

    // ---- fused per-(layer, amp-bit) 2x2 params ----
    if (tid < NL * NQ) {
        const int l = tid / NQ;
        const int b = tid % NQ;           // amp-bit position
        const int w = NQ - 1 - b;         // wire w acts on amp bit 11-w
        float hx = atanf(inputs[blk * NQ + w] * w_input2[w]) * 0.5f;
        float hy = y_weights[l * NQ + w] * 0.5f;
        float hz = (l == NL - 1) ? 0.0f : z_weights[l * NQ + w] * 0.5f;
        float cx, sx, cy, sy, cz, sz;
        __sincosf(hx, &sx, &cx);
        __sincosf(hy, &sy, &cy);
        __sincosf(hz, &sz, &cz);
        float A0r = cy * cx, A0i = sy * sx;       // RY*RX
        float B0r = -sy * cx, B0i = -cy * sx;
        gU[l][b] = make_float4(cz * A0r + sz * A0i, cz * A0i - sz * A0r,
                               cz * B0r + sz * B0i, cz * B0i - sz * B0r);
    }

    // ---- CZ-ring sign masks for phase-0 and phase-2 mappings ----
    int czm0 = 0, czm2 = 0;
    #pragma unroll
    for (int j = 0; j < AMPS; ++j) {
        int i0 = (tid << 3) | j;
        int r0 = ((i0 >> 1) | (i0 << (NQ - 1))) & (DIM - 1);
        czm0 |= (__popc(i0 & r0) & 1) << j;
        int i2 = (tid & 63) | (j << 6) | ((tid >> 6) << 9);
        int r2 = ((i2 >> 1) | (i2 << (NQ - 1))) & (DIM - 1);
        czm2 |= (__popc(i2 & r2) & 1) << j;
    }

    float2 s[AMPS];

    auto apply_gate = [&](float4 u, int lb) {
        const float Ar = u.x, Ai = u.y, Br = u.z, Bi = u.w;
        #pragma unroll
        for (int j0 = 0; j0 < AMPS; ++j0) {
            if (j0 & (1 << lb)) continue;
            const int j1 = j0 | (1 << lb);
            float r0 = s[j0].x, i0 = s[j0].y;
            float r1 = s[j1].x, i1 = s[j1].y;
            s[j0].x =  Ar * r0 - Ai * i0 + Br * r1 - Bi * i1;
            s[j0].y =  Ar * i0 + Ai * r0 + Br * i1 + Bi * r1;
            s[j1].x = -Br * r0 - Bi * i0 + Ar * r1 + Ai * i1;
            s[j1].y = -Br * i0 + Bi * r0 + Ar * i1 - Ai * r1;
        }
    };
    auto apply_phase = [&](int l, int k) {   // 3 gates on local bits of phase k
        #pragma unroll
        for (int lb = 0; lb < 3; ++lb) apply_gate(gU[l][3 * k + lb], lb);
    };
    auto transpose = [&](float2* buf, int pf, int pt) {  // one barrier (A/B alternate)
        #pragma unroll
        for (int j = 0; j < AMPS; ++j) buf[swz(amp_of(pf, tid, j))] = s[j];
        __syncthreads();
        #pragma unroll
        for (int j = 0; j < AMPS; ++j) s[j] = buf[swz(amp_of(pt, tid, j))];
    };
    auto czapply = [&](int mask) {
        #pragma unroll
        for (int j = 0; j < AMPS; ++j) {
            unsigned sb = ((unsigned)((mask >> j) & 1)) << 31;
            s[j].x = __uint_as_float(__float_as_uint(s[j].x) ^ sb);
            s[j].y = __uint_as_float(__float_as_uint(s[j].y) ^ sb);
        }
    };

    __syncthreads();                      // gU ready

    // ---- layer 0 as product state, phase-0 mapping: amp = (tid<<3)|j ----
    {
        auto selv = [&](int b, int bit) -> float2 {   // U|0> = (A, -conj(B))
            float4 u = gU[0][b];
            return bit ? make_float2(-u.z, u.w) : make_float2(u.x, u.y);
        };
        float2 P = selv(11, (tid >> 8) & 1);
        #pragma unroll
        for (int b = 10; b >= 3; --b) {
            float2 f = selv(b, (tid >> (b - 3)) & 1);
            P = make_float2(P.x * f.x - P.y * f.y, P.x * f.y + P.y * f.x);
        }
        float2 q0[2] = { selv(0, 0), selv(0, 1) };
        float2 q1[2] = { selv(1, 0), selv(1, 1) };
        float2 q2[2] = { selv(2, 0), selv(2, 1) };
        #pragma unroll
        for (int j = 0; j < AMPS; ++j) {
            float2 a = q1[(j >> 1) & 1], b2 = q0[j & 1];
            float2 t = make_float2(a.x * b2.x - a.y * b2.y, a.x * b2.y + a.y * b2.x);
            float2 c = q2[(j >> 2) & 1];
            float2 u = make_float2(c.x * t.x - c.y * t.y, c.x * t.y + c.y * t.x);
            s[j] = make_float2(P.x * u.x - P.y * u.y, P.x * u.y + P.y * u.x);
        }
    }
    czapply(czm0);                        // layer-0 CZ ring

    // ---- layer 1: phase path 0 -> 1 -> 3 -> 2 (all 12 gates) ----
    apply_phase(1, 0); transpose(xA, 0, 1);
    apply_phase(1, 1); transpose(xB, 1, 3);
    apply_phase(1, 3); transpose(xA, 3, 2);
    apply_phase(1, 2);
    czapply(czm2);                        // layer-1 CZ ring (phase-2 mapping)

    // ---- layer 2: only wires 0..3 (amp bits 11..8) survive ----
    apply_gate(gU[2][8], 2);              // bit 8 local at phase 2 (lb=2)
    transpose(xB, 2, 3);
    apply_phase(2, 3);                    // bits 9,10,11

    // ---- expectations at phase-3 mapping: amp = tid | (j<<9) ----
    // Z0Z1 -> amp bits 11,10 = j2,j1 ; Z2Z3 -> amp bits 9,8 = j0, tid bit 8
    float e0 = 0.0f, in1 = 0.0f;
    #pragma unroll
    for (int j = 0; j < AMPS; ++j) {
        float pw = s[j].x * s[j].x + s[j].y * s[j].y;
        e0  += (((j >> 2) ^ (j >> 1)) & 1) ? -pw : pw;
        in1 += (j & 1) ? -pw : pw;
    }
    float e1 = (tid & 256) ? -in1 : in1;
    #pragma unroll
    for (int off = 32; off; off >>= 1) {
        e0 += __shfl_down(e0, off);
        e1 += __shfl_down(e1, off);
    }
    const int wv = tid >> 6;
    if ((tid & 63) == 0) { rb0[wv] = e0; rb1[wv] = e1; }
    __syncthreads();
    if (tid == 0) {
        float t0 = 0.0f, t1 = 0.0f;
        #pragma unroll
        for (int i = 0; i < 8; ++i) { t0 += rb0[i]; t1 += rb1[i]; }
        out[blk * 2 + 0] = (1.0f + t0) * 0.5f * w_output2[0];
        out[blk * 2 + 1] = (1.0f + t1) * 0.5f * w_output2[1];
    }
}

extern "C" void kernel_launch(void* const* d_in, const int* in_sizes, int n_in,
                              void* d_out, int out_size, void* d_ws, size_t ws_size,
                              hipStream_t stream) {
    const float* inputs    = (const float*)d_in[0];
    const float* w_input2  = (const float*)d_in[1];
    const float* w_output2 = (const float*)d_in[2];
    const float* y_weights = (const float*)d_in[3];
    const float* z_weights = (const float*)d_in[4];
    float* out = (float*)d_out;
    qdqn_kernel<<<NB, NT, 0, stream>>>(inputs, w_input2, w_output2,
                                       y_weights, z_weights, out);
}

// Round 5
// 9.686 us; speedup vs baseline: 6.0247x; 1.8745x over previous
//
#include <hip/hip_runtime.h>
#include <math.h>

#define NQ 12
#define NB 512

typedef float2 cplx;
__device__ __forceinline__ cplx cmul(cplx a, cplx b) { return make_float2(a.x*b.x - a.y*b.y, a.x*b.y + a.y*b.x); }
__device__ __forceinline__ cplx cconj(cplx a) { return make_float2(a.x, -a.y); }
__device__ __forceinline__ cplx cadd(cplx a, cplx b) { return make_float2(a.x+b.x, a.y+b.y); }
__device__ __forceinline__ cplx csub(cplx a, cplx b) { return make_float2(a.x-b.x, a.y-b.y); }
__device__ __forceinline__ cplx cscale(cplx a, float s) { return make_float2(a.x*s, a.y*s); }
__device__ __forceinline__ cplx cneg(cplx a) { return make_float2(-a.x, -a.y); }

// E_obs = sum of 4 terms, each Tr( D_{p-1} S D_p S D_{p+1} S D_{p+2} S * R_I ),
// R_I (8 identity sites) is exactly rank-1 (since |v0|^2+|v1|^2 = 1):
//   R_I = u c^T,  u from wire p+3, c from wire p-2.
// Chain: t = S u = (1, d(p+3), d(p+3), 1); apply D at wires p+2,p+1,p,p-1 with
// butterflies between; E = t0 + d(p-2)*(t1+t2) + t3.
__global__ __launch_bounds__(64) void qdqn_kernel(
    const float* __restrict__ inputs,     // [NB, NQ]
    const float* __restrict__ w_input2,   // [NQ]
    const float* __restrict__ w_output2,  // [2]
    const float* __restrict__ y_weights,  // [3, NQ]
    const float* __restrict__ z_weights,  // [3, NQ]
    float* __restrict__ out)              // [NB, 2]
{
    __shared__ float sP0[NQ], sP1[NQ], sDL[NQ], sZA[NQ], sA2[4];
    __shared__ cplx  sV0[NQ], sV1[NQ], sZB[NQ];
    __shared__ cplx  sA1[4], sB1[4], sEP[4], sB2[4];

    const int tid = threadIdx.x;
    const int blk = blockIdx.x;

    // ---- per-wire setup (12 threads) ----
    if (tid < NQ) {
        const int w = tid;
        float t  = inputs[blk * NQ + w] * w_input2[w];
        float hx = 0.5f * atanf(t);
        float cx, sx; __sincosf(hx, &sx, &cx);

        // layer 0: v = RZ(z0)*RY(y0)*RX(x)|0>
        float hy0 = 0.5f * y_weights[w];
        float cy0, sy0; __sincosf(hy0, &sy0, &cy0);
        float hz0 = 0.5f * z_weights[w];
        float c0, s0; __sincosf(hz0, &s0, &c0);
        float ar = cy0 * cx, ai = sy0 * sx;            // A0
        cplx v0 = make_float2(c0 * ar + s0 * ai, c0 * ai - s0 * ar);   // e^{-i hz0} A0
        float br = sy0 * cx, bi = -cy0 * sx;           // -conj(B0)
        cplx v1 = make_float2(c0 * br - s0 * bi, c0 * bi + s0 * br);   // e^{+i hz0}(-conj B0)
        float p0 = v0.x * v0.x + v0.y * v0.y;
        float p1 = v1.x * v1.x + v1.y * v1.y;
        sV0[w] = v0; sV1[w] = v1; sP0[w] = p0; sP1[w] = p1; sDL[w] = p0 - p1;

        // layer 1: V1 = RY(y1)*RX(x); Ztilde = V1^dag Z V1 (RZ1 drops)
        float hy1 = 0.5f * y_weights[NQ + w];
        float cy1, sy1; __sincosf(hy1, &sy1, &cy1);
        cplx A1 = make_float2(cy1 * cx, sy1 * sx);
        cplx B1 = make_float2(-sy1 * cx, -cy1 * sx);
        sZA[w] = (A1.x*A1.x + A1.y*A1.y) - (B1.x*B1.x + B1.y*B1.y);
        cplx bt = cmul(cconj(A1), B1);
        sZB[w] = make_float2(2.0f * bt.x, 2.0f * bt.y);

        if (w < 4) {                                   // wires used by F-type ops
            sA1[w] = A1; sB1[w] = B1;
            float th = z_weights[NQ + w];              // FULL layer-1 z angle
            float cth, sth; __sincosf(th, &sth, &cth);
            sEP[w] = make_float2(cth, sth);
            float hy2 = 0.5f * y_weights[2 * NQ + w];
            float cy2, sy2; __sincosf(hy2, &sy2, &cy2);
            cplx A2 = make_float2(cy2 * cx, sy2 * sx);
            cplx B2 = make_float2(-sy2 * cx, -cy2 * sx);
            sA2[w] = (A2.x*A2.x + A2.y*A2.y) - (B2.x*B2.x + B2.y*B2.y);
            cplx b2 = cmul(cconj(A2), B2);
            sB2[w] = make_float2(2.0f * b2.x, 2.0f * b2.y);
        }
    }
    __syncthreads();

    float eout = 0.0f;
    if (tid < 8) {
        const int obs = tid >> 2, term = tid & 3;
        const int p = obs * 2;                        // observable wires (p, p+1)
        const int wm1 = (p + 11) % 12, wp = p, wp1 = p + 1, wp2 = p + 2;
        const int wins[4] = { wm1, wp, wp1, wp2 };

        cplx dW[4][4];                                // [site][bond state]
        #pragma unroll
        for (int i = 0; i < 4; ++i) {                 // identity defaults
            dW[i][0] = make_float2(sP0[wins[i]], 0.0f);
            dW[i][1] = make_float2(0.0f, 0.0f);
            dW[i][2] = make_float2(0.0f, 0.0f);
            dW[i][3] = make_float2(sP1[wins[i]], 0.0f);
        }
        auto setKMN = [&](int i, int w, cplx k, cplx m, cplx n) {
            cplx v0 = sV0[w], v1 = sV1[w];
            dW[i][0] = cscale(k, sP0[w]);
            dW[i][1] = cmul(cmul(cconj(v0), m), v1);
            dW[i][2] = cmul(cmul(cconj(v1), n), v0);
            dW[i][3] = cscale(k, -sP1[w]);
        };
        auto setZ = [&](int i, int w) {
            cplx m = sZB[w];
            setKMN(i, w, make_float2(sZA[w], 0.0f), m, cconj(m));
        };
        // type 0: Ftilde (g=beta, d=conj beta); 1: (F*Z)~ (g=-beta, d=conj beta);
        // 2: (Z*F)~ (g=beta, d=-conj beta).  beta = b2 * e^{i z1}.
        auto setF = [&](int i, int w, int type) {
            cplx beta = cmul(sB2[w], sEP[w]);
            cplx gam = (type == 1) ? cneg(beta) : beta;
            cplx del = (type == 2) ? cneg(cconj(beta)) : cconj(beta);
            cplx A = sA1[w], B = sB1[w];
            cplx cA = cconj(A), cB = cconj(B);
            cplx k = cneg(cadd(cmul(gam, cmul(cA, cB)), cmul(del, cmul(A, B))));
            cplx m = csub(cmul(gam, cmul(cA, cA)), cmul(del, cmul(B, B)));
            cplx n = csub(cmul(del, cmul(A, A)), cmul(gam, cmul(cB, cB)));
            setKMN(i, w, k, m, n);
        };

        float coeff;
        if (term == 0)      { coeff = sA2[p] * sA2[p + 1]; setZ(1, wp);  setZ(2, wp1); }
        else if (term == 1) { coeff = sA2[p];              setF(2, wp1, 0); setZ(3, wp2); }
        else if (term == 2) { coeff = sA2[p + 1];          setZ(0, wm1); setF(1, wp, 0); }
        else                { coeff = 1.0f;                setZ(0, wm1); setF(1, wp, 1);
                                                           setF(2, wp1, 2); setZ(3, wp2); }

        const float dU = sDL[p + 3];                  // wire p+3 (u-side)
        const float dC = sDL[(p + 10) % 12];          // wire p-2 (c-side)
        cplx t0 = make_float2(1.0f, 0.0f), t1 = make_float2(dU, 0.0f);
        cplx t2 = t1, t3 = t0;
        auto appD = [&](int i) {
            t0 = cmul(t0, dW[i][0]); t1 = cmul(t1, dW[i][1]);
            t2 = cmul(t2, dW[i][2]); t3 = cmul(t3, dW[i][3]);
        };
        auto bfly = [&]() {
            cplx a0 = cadd(t0, t1), a1 = csub(t0, t1);
            cplx a2 = cadd(t2, t3), a3 = csub(t2, t3);
            t0 = cadd(a0, a2); t1 = cadd(a1, a3);
            t2 = csub(a0, a2); t3 = csub(a1, a3);
        };
        appD(3); bfly(); appD(2); bfly(); appD(1); bfly(); appD(0);
        float E = t0.x + dC * (t1.x + t2.x) + t3.x;
        eout = coeff * E;
    }

    // sum the 4 terms within each obs group (threads 0..7, groups of 4)
    eout += __shfl_down(eout, 1);
    eout += __shfl_down(eout, 2);
    if (tid < 8 && (tid & 3) == 0) {
        const int obs = tid >> 2;
        out[blk * 2 + obs] = (1.0f + eout) * 0.5f * w_output2[obs];
    }
}

extern "C" void kernel_launch(void* const* d_in, const int* in_sizes, int n_in,
                              void* d_out, int out_size, void* d_ws, size_t ws_size,
                              hipStream_t stream) {
    const float* inputs    = (const float*)d_in[0];
    const float* w_input2  = (const float*)d_in[1];
    const float* w_output2 = (const float*)d_in[2];
    const float* y_weights = (const float*)d_in[3];
    const float* z_weights = (const float*)d_in[4];
    float* out = (float*)d_out;
    qdqn_kernel<<<NB, 64, 0, stream>>>(inputs, w_input2, w_output2,
                                       y_weights, z_weights, out);
}

// Round 7
// 9.610 us; speedup vs baseline: 6.0724x; 1.0079x over previous
//
#include <hip/hip_runtime.h>
#include <math.h>

#define NQ   12
#define NB   512
#define GPB  4                 // batch elements per 64-thread block (16-lane groups)
#define NBLK (NB / GPB)        // 128 blocks

typedef float2 cplx;
__device__ __forceinline__ cplx cmul(cplx a, cplx b) { return make_float2(a.x*b.x - a.y*b.y, a.x*b.y + a.y*b.x); }
__device__ __forceinline__ cplx cconj(cplx a) { return make_float2(a.x, -a.y); }
__device__ __forceinline__ cplx cadd(cplx a, cplx b) { return make_float2(a.x+b.x, a.y+b.y); }
__device__ __forceinline__ cplx csub(cplx a, cplx b) { return make_float2(a.x-b.x, a.y-b.y); }
__device__ __forceinline__ cplx cscale(cplx a, float s) { return make_float2(a.x*s, a.y*s); }
__device__ __forceinline__ cplx cneg(cplx a) { return make_float2(-a.x, -a.y); }

// Transfer-matrix closed form (validated round 5, absmax 0.0).
// Port rule learned round 6: ALL __shfl gathers must execute CONVERGENTLY
// (ds_bpermute from an EXEC-inactive source lane is undefined). So every
// cross-lane read is hoisted above the per-term branches; branches use only
// register data.
__global__ __launch_bounds__(64) void qdqn_kernel(
    const float* __restrict__ inputs,     // [NB, NQ]
    const float* __restrict__ w_input2,   // [NQ]
    const float* __restrict__ w_output2,  // [2]
    const float* __restrict__ y_weights,  // [3, NQ]
    const float* __restrict__ z_weights,  // [3, NQ]
    float* __restrict__ out)              // [NB, 2]
{
    const int lane  = threadIdx.x & 63;
    const int sub   = lane & 15;          // position within 16-lane group
    const int base  = lane & 48;          // group's base lane
    const int batch = blockIdx.x * GPB + (lane >> 4);

    // ---- per-wire setup, all lanes (wire = sub, clamped for sub>=12) ----
    const int w = (sub >= NQ) ? (sub - NQ) : sub;

    float t = inputs[batch * NQ + w] * w_input2[w];
    // cos/sin of atan(t)/2 without atan: c = cos(atan t) = rsqrt(1+t^2)
    float c  = rsqrtf(1.0f + t * t);
    float rh = rsqrtf(0.5f * (1.0f + c));
    float cx = 0.5f * (1.0f + c) * rh;            // cos(atan(t)/2)
    float sx = 0.5f * t * c * rh;                 // sin(atan(t)/2)

    // layer 0: v = RZ(z0)*RY(y0)*RX(x)|0>
    float hy0 = 0.5f * y_weights[w];
    float cy0, sy0; __sincosf(hy0, &sy0, &cy0);
    float hz0 = 0.5f * z_weights[w];
    float c0, s0; __sincosf(hz0, &s0, &c0);
    float ar = cy0 * cx, ai = sy0 * sx;
    cplx v0 = make_float2(c0 * ar + s0 * ai, c0 * ai - s0 * ar);
    float br = sy0 * cx, bi = -cy0 * sx;
    cplx v1 = make_float2(c0 * br - s0 * bi, c0 * bi + s0 * br);
    float p0 = v0.x * v0.x + v0.y * v0.y;
    float p1 = v1.x * v1.x + v1.y * v1.y;
    float dl = p0 - p1;

    // layer 1: V1 = RY(y1)*RX(x); Ztilde = V1^dag Z V1
    float hy1 = 0.5f * y_weights[NQ + w];
    float cy1, sy1; __sincosf(hy1, &sy1, &cy1);
    cplx A1 = make_float2(cy1 * cx, sy1 * sx);
    cplx B1 = make_float2(-sy1 * cx, -cy1 * sx);
    float za = (A1.x*A1.x + A1.y*A1.y) - (B1.x*B1.x + B1.y*B1.y);
    cplx bt = cmul(cconj(A1), B1);
    cplx zb = make_float2(2.0f * bt.x, 2.0f * bt.y);

    // F-op extras (used only for wires 0..3, computed uniformly)
    float th1 = z_weights[NQ + w];                // FULL layer-1 z angle
    float cth, sth; __sincosf(th1, &sth, &cth);
    cplx ep = make_float2(cth, sth);
    float hy2 = 0.5f * y_weights[2 * NQ + w];
    float cy2, sy2; __sincosf(hy2, &sy2, &cy2);
    cplx A2 = make_float2(cy2 * cx, sy2 * sx);
    cplx B2 = make_float2(-sy2 * cx, -cy2 * sx);
    float a2 = (A2.x*A2.x + A2.y*A2.y) - (B2.x*B2.x + B2.y*B2.y);
    cplx b2c = cmul(cconj(A2), B2);
    cplx b2 = make_float2(2.0f * b2c.x, 2.0f * b2c.y);

    // ---- gather helpers (CONVERGENT use only) ----
    auto SHf = [&](const float& v, int ww) -> float { return __shfl(v, base + ww); };
    auto SHc = [&](const cplx& v, int ww) -> cplx {
        return make_float2(__shfl(v.x, base + ww), __shfl(v.y, base + ww));
    };

    const int obs = (sub >> 2) & 1, term = sub & 3;
    const int p = obs * 2;
    const int wm1 = (p + 11) % 12, wp = p, wp1 = p + 1, wp2 = p + 2;
    const int wins[4] = { wm1, wp, wp1, wp2 };

    // ---- ALL cross-lane gathers, fully convergent ----
    float p0s[4], p1s[4], zas[4];
    cplx  v0s[4], v1s[4], zbs[4];
    #pragma unroll
    for (int i = 0; i < 4; ++i) {
        const int ww = wins[i];
        p0s[i] = SHf(p0, ww);  p1s[i] = SHf(p1, ww);
        v0s[i] = SHc(v0, ww);  v1s[i] = SHc(v1, ww);
        zas[i] = SHf(za, ww);  zbs[i] = SHc(zb, ww);
    }
    cplx A1w[2], B1w[2], betw[2];          // F-sites: fs=0 -> wire wp, fs=1 -> wire wp1
    #pragma unroll
    for (int i = 0; i < 2; ++i) {
        const int ww = p + i;
        A1w[i] = SHc(A1, ww);  B1w[i] = SHc(B1, ww);
        betw[i] = cmul(SHc(b2, ww), SHc(ep, ww));
    }
    const float a2p  = SHf(a2, p);
    const float a2p1 = SHf(a2, p + 1);
    const float dU   = SHf(dl, p + 3);
    const float dC   = SHf(dl, (p == 0) ? 10 : 0);   // (p+10)%12

    // ---- build dW (register-only from here on; branch-safe) ----
    cplx dW[4][4];
    #pragma unroll
    for (int i = 0; i < 4; ++i) {                 // identity defaults
        dW[i][0] = make_float2(p0s[i], 0.0f);
        dW[i][1] = make_float2(0.0f, 0.0f);
        dW[i][2] = make_float2(0.0f, 0.0f);
        dW[i][3] = make_float2(p1s[i], 0.0f);
    }
    auto setKMN = [&](int i, cplx k, cplx m, cplx n) {
        dW[i][0] = cscale(k, p0s[i]);
        dW[i][1] = cmul(cmul(cconj(v0s[i]), m), v1s[i]);
        dW[i][2] = cmul(cmul(cconj(v1s[i]), n), v0s[i]);
        dW[i][3] = cscale(k, -p1s[i]);
    };
    auto setZ = [&](int i) {
        setKMN(i, make_float2(zas[i], 0.0f), zbs[i], cconj(zbs[i]));
    };
    // type 0: g=beta, d=conj beta; 1: g=-beta, d=conj beta; 2: g=beta, d=-conj beta
    auto setF = [&](int i, int fs, int type) {
        cplx beta = betw[fs];
        cplx gam = (type == 1) ? cneg(beta) : beta;
        cplx del = (type == 2) ? cneg(cconj(beta)) : cconj(beta);
        cplx A = A1w[fs], B = B1w[fs];
        cplx cA = cconj(A), cB = cconj(B);
        cplx k = cneg(cadd(cmul(gam, cmul(cA, cB)), cmul(del, cmul(A, B))));
        cplx m = csub(cmul(gam, cmul(cA, cA)), cmul(del, cmul(B, B)));
        cplx n = csub(cmul(del, cmul(A, A)), cmul(gam, cmul(cB, cB)));
        setKMN(i, k, m, n);
    };

    float coeff;
    if (term == 0)      { coeff = a2p * a2p1; setZ(1); setZ(2); }
    else if (term == 1) { coeff = a2p;        setF(2, 1, 0); setZ(3); }
    else if (term == 2) { coeff = a2p1;       setZ(0); setF(1, 0, 0); }
    else                { coeff = 1.0f;       setZ(0); setF(1, 0, 1);
                                              setF(2, 1, 2); setZ(3); }

    // ---- transfer chain ----
    cplx t0 = make_float2(1.0f, 0.0f), t1 = make_float2(dU, 0.0f);
    cplx t2 = t1, t3 = t0;
    auto appD = [&](int i) {
        t0 = cmul(t0, dW[i][0]); t1 = cmul(t1, dW[i][1]);
        t2 = cmul(t2, dW[i][2]); t3 = cmul(t3, dW[i][3]);
    };
    auto bfly = [&]() {
        cplx a0 = cadd(t0, t1), a1 = csub(t0, t1);
        cplx a2v = cadd(t2, t3), a3 = csub(t2, t3);
        t0 = cadd(a0, a2v); t1 = cadd(a1, a3);
        t2 = csub(a0, a2v); t3 = csub(a1, a3);
    };
    appD(3); bfly(); appD(2); bfly(); appD(1); bfly(); appD(0);
    float E = t0.x + dC * (t1.x + t2.x) + t3.x;
    float eout = coeff * E;

    // sum 4 terms within each aligned 4-lane cluster (convergent)
    eout += __shfl_xor(eout, 1);
    eout += __shfl_xor(eout, 2);
    if (sub < 8 && (sub & 3) == 0) {
        out[batch * 2 + obs] = (1.0f + eout) * 0.5f * w_output2[obs];
    }
}

extern "C" void kernel_launch(void* const* d_in, const int* in_sizes, int n_in,
                              void* d_out, int out_size, void* d_ws, size_t ws_size,
                              hipStream_t stream) {
    const float* inputs    = (const float*)d_in[0];
    const float* w_input2  = (const float*)d_in[1];
    const float* w_output2 = (const float*)d_in[2];
    const float* y_weights = (const float*)d_in[3];
    const float* z_weights = (const float*)d_in[4];
    float* out = (float*)d_out;
    qdqn_kernel<<<NBLK, 64, 0, stream>>>(inputs, w_input2, w_output2,
                                         y_weights, z_weights, out);
}